// Round 7
// baseline (938.287 us; speedup 1.0000x reference)
//
#include <hip/hip_runtime.h>
#include <hip/hip_bf16.h>
#include <stdint.h>

typedef __attribute__((ext_vector_type(8))) short short8;       // 8 bf16 (MFMA frag)
typedef __attribute__((ext_vector_type(4))) float f32x4;
typedef __attribute__((ext_vector_type(8))) unsigned short u16x8;

static __device__ __forceinline__ unsigned short f2bf(float f) {
  union { float f; unsigned int u; } c; c.f = f;
  unsigned int u = c.u;
  u += 0x7FFFu + ((u >> 16) & 1u);
  return (unsigned short)(u >> 16);
}
static __device__ __forceinline__ float bf2f(unsigned short h) {
  union { unsigned int u; float f; } c; c.u = ((unsigned int)h) << 16;
  return c.f;
}
static __device__ __forceinline__ f32x4 mfma_bf16(short8 a, short8 b, f32x4 c) {
  return __builtin_amdgcn_mfma_f32_16x16x32_bf16(a, b, c, 0, 0, 0);
}
static __device__ __forceinline__ void gl_lds16(const void* g, void* lds) {
  __builtin_amdgcn_global_load_lds(
      (const __attribute__((address_space(1))) void*)(unsigned long long)(uintptr_t)g,
      (__attribute__((address_space(3))) void*)(unsigned int)(uintptr_t)lds,
      16, 0, 0);
}

// ---------------------------------------------------------------------------
// convert kernels
// ---------------------------------------------------------------------------
__global__ void k_cvt_w(const float* __restrict__ w, const float* __restrict__ s,
                        unsigned short* __restrict__ o, int N, int K) {
  const int KB = K >> 7;
  const size_t total = ((size_t)N * K) >> 3;
  for (size_t i = (size_t)blockIdx.x * blockDim.x + threadIdx.x; i < total;
       i += (size_t)gridDim.x * blockDim.x) {
    const size_t e = i << 3;
    const int n = (int)(e / K);
    const int k = (int)(e % K);
    const float sc = s[(n >> 7) * KB + (k >> 7)];
    f32x4 a = *(const f32x4*)(w + e);
    f32x4 b = *(const f32x4*)(w + e + 4);
    u16x8 q;
    #pragma unroll
    for (int j = 0; j < 4; ++j) { q[j] = f2bf(a[j] * sc); q[4 + j] = f2bf(b[j] * sc); }
    *(u16x8*)(o + e) = q;
  }
}

__global__ void k_cvt_x(const float* __restrict__ x, unsigned short* __restrict__ o,
                        size_t total8) {
  for (size_t i = (size_t)blockIdx.x * blockDim.x + threadIdx.x; i < total8;
       i += (size_t)gridDim.x * blockDim.x) {
    const size_t e = i << 3;
    f32x4 a = *(const f32x4*)(x + e);
    f32x4 b = *(const f32x4*)(x + e + 4);
    u16x8 q;
    #pragma unroll
    for (int j = 0; j < 4; ++j) { q[j] = f2bf(a[j]); q[4 + j] = f2bf(b[j]); }
    *(u16x8*)(o + e) = q;
  }
}

// ---------------------------------------------------------------------------
// 8-phase deep-pipelined GEMM (m201-style), RACE-FIXED (R6 post-mortem):
// every counted vmcnt sits IMMEDIATELY BEFORE a s_barrier, so all waves'
// DMA for a tile has landed before any wave's first ds_read of that tile.
//   - prologue: vmcnt(8/6) + barrier  (tile 0 ready)
//   - end P3:   vmcnt(6/4 | 0 last) + barrier (tile t1 ready for P4)
//   - end P7:   vmcnt(6/4) + barrier          (tile t0' ready for P0')
// Never 0 mid-loop. Overwrite-issue safety: each stage call sits behind a
// barrier whose preceding lgkmcnt(0) retired the target buffer's last reads.
// EPI: 0 = bf16 store; 1 = silu(Gin)*acc -> bf16; 2 = f32 store.
// ---------------------------------------------------------------------------
#define PH_MID() do { \
    __builtin_amdgcn_sched_barrier(0); \
    __builtin_amdgcn_s_barrier(); \
    asm volatile("s_waitcnt lgkmcnt(0)" ::: "memory"); \
    __builtin_amdgcn_sched_barrier(0); \
    __builtin_amdgcn_s_setprio(1); \
  } while (0)
#define PH_END() do { \
    __builtin_amdgcn_s_setprio(0); \
    __builtin_amdgcn_sched_barrier(0); \
    __builtin_amdgcn_s_barrier(); \
  } while (0)

#define READ_A(d, mh) do { \
    const char* _ba = (const char*)lds + ((d) * 2 + wm) * 16384; \
    _Pragma("unroll") \
    for (int f = 0; f < 4; ++f) { \
      aF[0][f] = *(const short8*)(_ba + ((((mh) * 64 + f * 16 + lr) * 128 + kg * 16) ^ xr)); \
      aF[1][f] = *(const short8*)(_ba + ((((mh) * 64 + f * 16 + lr) * 128 + 64 + kg * 16) ^ xr)); \
    } } while (0)
#define READ_B(d, nh, bF) do { \
    const char* _bb = (const char*)lds + ABYTES + ((d) * NBH + bhalf) * 16384; \
    _Pragma("unroll") \
    for (int f = 0; f < NH2; ++f) { \
      bF[0][f] = *(const short8*)(_bb + (((wrow0 + ((nh) * NH2 + f) * 16 + lr) * 128 + kg * 16) ^ xr)); \
      bF[1][f] = *(const short8*)(_bb + (((wrow0 + ((nh) * NH2 + f) * 16 + lr) * 128 + 64 + kg * 16) ^ xr)); \
    } } while (0)
#define MFMA_Q(mh, nh, bF) do { \
    _Pragma("unroll") \
    for (int m = 0; m < 4; ++m) \
      _Pragma("unroll") \
      for (int n = 0; n < NH2; ++n) { \
        acc[(mh) * 4 + m][(nh) * NH2 + n] = \
            mfma_bf16(aF[0][m], bF[0][n], acc[(mh) * 4 + m][(nh) * NH2 + n]); \
        acc[(mh) * 4 + m][(nh) * NH2 + n] = \
            mfma_bf16(aF[1][m], bF[1][n], acc[(mh) * 4 + m][(nh) * NH2 + n]); \
      } } while (0)

template<int NB, int EPI>
__global__ __launch_bounds__(512, 2)
void k_gemm8p(const unsigned short* __restrict__ A,
              const unsigned short* __restrict__ B,
              const unsigned short* Gin,
              void* Out,
              int M, int N, int K) {
  constexpr int BN     = NB * 128;
  constexpr int NREP   = NB * 2;
  constexpr int NH2    = NREP / 2;
  constexpr int NBH    = NB;
  constexpr int ABYTES = 65536;
  __shared__ unsigned short lds[(NB == 2) ? 65536 : 49152];

  const int tid  = threadIdx.x;
  const int lane = tid & 63;
  const int wid  = tid >> 6;
  const int wm   = wid >> 2;
  const int wn   = wid & 3;
  const int lr   = lane & 15;
  const int kg   = lane >> 4;
  const int xr   = (lr & 7) << 4;

  const int nwg = gridDim.x;
  const int per = nwg >> 3;
  const int wg  = (int)blockIdx.x;
  const int swz = (wg & 7) * per + (wg >> 3);
  const int bm  = swz & 7;
  const int bn  = swz >> 3;

  const int r0   = tid >> 3;
  const int colb = ((tid & 7) ^ ((tid >> 3) & 7)) << 4;
  const size_t ldb = (size_t)K * 2;

  const char* gA = (const char*)A + (size_t)bm * 256 * ldb;
  const char* gB = (const char*)B + (size_t)bn * BN * ldb;

  const int wrow0 = (NB == 2) ? (wn & 1) * 64 : wn * 32;
  const int bhalf = (NB == 2) ? (wn >> 1) : 0;

  auto stageA = [&](int t, int h) {
    unsigned short* d = lds + ((t & 1) * 2 + h) * 8192 + wid * 512;
    const char* s = gA + (size_t)(h * 128 + r0) * ldb + (size_t)t * 128 + colb;
    gl_lds16(s, d);
    gl_lds16(s + 64 * ldb, d + 4096);
  };
  auto stageB = [&](int t, int h) {
    unsigned short* d = lds + (ABYTES / 2) + ((t & 1) * NBH + h) * 8192 + wid * 512;
    const char* s = gB + (size_t)(h * 128 + r0) * ldb + (size_t)t * 128 + colb;
    gl_lds16(s, d);
    gl_lds16(s + 64 * ldb, d + 4096);
  };

  f32x4 acc[8][NREP];
  #pragma unroll
  for (int m = 0; m < 8; ++m)
    #pragma unroll
    for (int n = 0; n < NREP; ++n)
      #pragma unroll
      for (int e = 0; e < 4; ++e) acc[m][n][e] = 0.0f;

  short8 aF[2][4], bF0[2][NH2], bF1[2][NH2];

  const int NP = K >> 7;

  // prologue: stage tiles 0,1 fully (oldest-first), then tile0-ready barrier
  stageB(0, 0); if constexpr (NB == 2) stageB(0, 1);
  stageA(0, 0); stageA(0, 1);
  stageB(1, 0); if constexpr (NB == 2) stageB(1, 1);
  stageA(1, 0); stageA(1, 1);
  if constexpr (NB == 2) asm volatile("s_waitcnt vmcnt(8)" ::: "memory");
  else                   asm volatile("s_waitcnt vmcnt(6)" ::: "memory");
  __builtin_amdgcn_sched_barrier(0);
  __builtin_amdgcn_s_barrier();      // ALL waves' tile-0 DMA landed

  for (int i = 0; i < NP; ++i) {
    const int t0 = 2 * i, t1 = 2 * i + 1;
    const bool more = (i + 1 < NP);

    // ---- P0: tile t0 (d0), quadrant (0,0) ----   [tile t0 ready-verified]
    READ_A(0, 0);
    READ_B(0, 0, bF0);
    if (i > 0) stageA(t1, 1);
    PH_MID(); MFMA_Q(0, 0, bF0); PH_END();

    // ---- P1: quadrant (0,1) ----
    READ_B(0, 1, bF1);
    PH_MID(); MFMA_Q(0, 1, bF1); PH_END();

    // ---- P2: quadrant (1,1) ----
    READ_A(0, 1);
    if (more) stageB(t0 + 2, 0);
    PH_MID(); MFMA_Q(1, 1, bF1); PH_END();

    // ---- P3: quadrant (1,0); end-wait: tile t1 ready for P4 ----
    if (more) { if constexpr (NB == 2) stageB(t0 + 2, 1); stageA(t0 + 2, 0); }
    PH_MID(); MFMA_Q(1, 0, bF0);
    __builtin_amdgcn_s_setprio(0);
    __builtin_amdgcn_sched_barrier(0);
    if (more) {
      if constexpr (NB == 2) asm volatile("s_waitcnt vmcnt(6)" ::: "memory");
      else                   asm volatile("s_waitcnt vmcnt(4)" ::: "memory");
    } else {
      asm volatile("s_waitcnt vmcnt(0)" ::: "memory");
    }
    __builtin_amdgcn_sched_barrier(0);
    __builtin_amdgcn_s_barrier();    // ALL waves' tile-t1 DMA landed

    // ---- P4: tile t1 (d1), quadrant (0,0) ----
    READ_A(1, 0);
    READ_B(1, 0, bF0);
    if (more) stageA(t0 + 2, 1);
    PH_MID(); MFMA_Q(0, 0, bF0); PH_END();

    // ---- P5: quadrant (0,1) ----
    READ_B(1, 1, bF1);
    PH_MID(); MFMA_Q(0, 1, bF1); PH_END();

    // ---- P6: quadrant (1,1) ----
    READ_A(1, 1);
    if (more) stageB(t1 + 2, 0);
    PH_MID(); MFMA_Q(1, 1, bF1); PH_END();

    // ---- P7: quadrant (1,0); end-wait: tile t0+2 ready for next P0 ----
    if (more) { if constexpr (NB == 2) stageB(t1 + 2, 1); stageA(t1 + 2, 0); }
    PH_MID(); MFMA_Q(1, 0, bF0);
    __builtin_amdgcn_s_setprio(0);
    __builtin_amdgcn_sched_barrier(0);
    if (more) {
      if constexpr (NB == 2) asm volatile("s_waitcnt vmcnt(6)" ::: "memory");
      else                   asm volatile("s_waitcnt vmcnt(4)" ::: "memory");
    }
    __builtin_amdgcn_sched_barrier(0);
    __builtin_amdgcn_s_barrier();    // tile t0+2 landed (when more)
  }

  // epilogue: C/D map col=lane&15, row=(lane>>4)*4+j  [m89-verified, R1-R5]
  const int growb = bm * 256 + wm * 128 + kg * 4;
  const int gcolb = bn * BN + wn * (BN / 4) + lr;
  #pragma unroll
  for (int m = 0; m < 8; ++m)
    #pragma unroll
    for (int n = 0; n < NREP; ++n)
      #pragma unroll
      for (int j = 0; j < 4; ++j) {
        const size_t idx = (size_t)(growb + m * 16 + j) * N + (gcolb + n * 16);
        if constexpr (EPI == 0) {
          ((unsigned short*)Out)[idx] = f2bf(acc[m][n][j]);
        } else if constexpr (EPI == 1) {
          const float gv = bf2f(Gin[idx]);
          const float sg = gv / (1.0f + __expf(-gv));
          ((unsigned short*)Out)[idx] = f2bf(sg * acc[m][n][j]);
        } else {
          ((float*)Out)[idx] = acc[m][n][j];
        }
      }
}

extern "C" void kernel_launch(void* const* d_in, const int* in_sizes, int n_in,
                              void* d_out, int out_size, void* d_ws, size_t ws_size,
                              hipStream_t stream) {
  const float* x   = (const float*)d_in[0];
  const float* w1  = (const float*)d_in[1];
  const float* w1s = (const float*)d_in[2];
  const float* w3  = (const float*)d_in[3];
  const float* w3s = (const float*)d_in[4];
  const float* w2  = (const float*)d_in[5];
  const float* w2s = (const float*)d_in[6];
  float* y = (float*)d_out;

  const int D = 4096, I = 14336;
  const int T = in_sizes[0] / D;          // 2048

  const size_t xbB = (size_t)T * D * 2;
  const size_t wB  = (size_t)I * D * 2;

  char* ws = (char*)d_ws;
  unsigned short* xb  = (unsigned short*)(ws);
  unsigned short* w1b = (unsigned short*)(ws + xbB);
  unsigned short* w3b = (unsigned short*)(ws + xbB + wB);
  unsigned short* w2b = (unsigned short*)(ws + xbB + 2 * wB);
  unsigned short* g   = (unsigned short*)(ws + xbB + 3 * wB);   // g -> h in place

  k_cvt_x<<<2048, 256, 0, stream>>>(x, xb, ((size_t)T * D) >> 3);
  k_cvt_w<<<2048, 256, 0, stream>>>(w1, w1s, w1b, I, D);
  k_cvt_w<<<2048, 256, 0, stream>>>(w3, w3s, w3b, I, D);
  k_cvt_w<<<2048, 256, 0, stream>>>(w2, w2s, w2b, D, I);

  // gate: g = xb @ w1b^T           grid 8*56 = 448
  k_gemm8p<2, 0><<<dim3((T / 256) * (I / 256)), dim3(512), 0, stream>>>(
      xb, w1b, nullptr, g, T, I, D);
  // up:   h = silu(g) * (xb @ w3b^T), in-place over g
  k_gemm8p<2, 1><<<dim3((T / 256) * (I / 256)), dim3(512), 0, stream>>>(
      xb, w3b, g, g, T, I, D);
  // down: y = h @ w2b^T            grid 8*32 = 256 (BN=128)
  k_gemm8p<1, 2><<<dim3((T / 256) * (D / 128)), dim3(512), 0, stream>>>(
      g, w2b, nullptr, y, T, D, I);
}